// Round 3
// baseline (929.942 us; speedup 1.0000x reference)
//
#include <hip/hip_runtime.h>
#include <math.h>

#define N_NODES 50000
#define F 128          // feature width (IN == F_HID == 128)
#define NEDGE 800000
#define NB_SCAN 49     // ceil(N_NODES/1024)

// ---------------------------------------------------------------------------
// GEMM: O[n][c] = sum_k A[n][k]*W[k][c] + b[c];  A:[N,128], W:[128,128]
// blockIdx.y selects (Wl,bl,xl) vs (Wr,br,xr). BM=64, BN=128, BK=32.
// ---------------------------------------------------------------------------
__global__ __launch_bounds__(256) void gemm128(
    const float* __restrict__ A,
    const float* __restrict__ Wl, const float* __restrict__ bl,
    const float* __restrict__ Wr, const float* __restrict__ br,
    float* __restrict__ xl, float* __restrict__ xr)
{
    const float* W = blockIdx.y ? Wr : Wl;
    const float* b = blockIdx.y ? br : bl;
    float*       O = blockIdx.y ? xr : xl;

    __shared__ float As[32][68];   // transposed A tile, padded (272B rows, 16B-aligned)
    __shared__ float Ws[32][128];

    const int tid = threadIdx.x;
    const int tx = tid & 15, ty = tid >> 4;
    const int R0 = blockIdx.x * 64;

    float acc[4][8];
#pragma unroll
    for (int i = 0; i < 4; ++i)
#pragma unroll
        for (int j = 0; j < 8; ++j) acc[i][j] = 0.f;

    for (int kt = 0; kt < 4; ++kt) {
        // A tile 64x32 -> As (transposed)
#pragma unroll
        for (int i = 0; i < 2; ++i) {
            int f = tid + i * 256;          // 0..511
            int row = f >> 3, kq = f & 7;
            int gr = R0 + row;
            float4 v = make_float4(0.f, 0.f, 0.f, 0.f);
            if (gr < N_NODES) v = *(const float4*)&A[gr * F + kt * 32 + kq * 4];
            As[kq * 4 + 0][row] = v.x; As[kq * 4 + 1][row] = v.y;
            As[kq * 4 + 2][row] = v.z; As[kq * 4 + 3][row] = v.w;
        }
        // W tile 32x128
#pragma unroll
        for (int i = 0; i < 4; ++i) {
            int f = tid + i * 256;          // 0..1023
            int k = f >> 5, cq = f & 31;
            *(float4*)&Ws[k][cq * 4] = *(const float4*)&W[(kt * 32 + k) * F + cq * 4];
        }
        __syncthreads();
#pragma unroll
        for (int k = 0; k < 32; ++k) {
            float4 a4 = *(const float4*)&As[k][ty * 4];
            float4 w0 = *(const float4*)&Ws[k][tx * 8];
            float4 w1 = *(const float4*)&Ws[k][tx * 8 + 4];
            float av[4] = {a4.x, a4.y, a4.z, a4.w};
            float wv[8] = {w0.x, w0.y, w0.z, w0.w, w1.x, w1.y, w1.z, w1.w};
#pragma unroll
            for (int i = 0; i < 4; ++i)
#pragma unroll
                for (int j = 0; j < 8; ++j) acc[i][j] += av[i] * wv[j];
        }
        __syncthreads();
    }
#pragma unroll
    for (int i = 0; i < 4; ++i) {
        int gr = R0 + ty * 4 + i;
        if (gr < N_NODES) {
#pragma unroll
            for (int j = 0; j < 8; ++j) acc[i][j] += b[tx * 8 + j];
            *(float4*)&O[gr * F + tx * 8]     = make_float4(acc[i][0], acc[i][1], acc[i][2], acc[i][3]);
            *(float4*)&O[gr * F + tx * 8 + 4] = make_float4(acc[i][4], acc[i][5], acc[i][6], acc[i][7]);
        }
    }
}

// ---------------------------------------------------------------------------
// CSR build: deg (init 1 for self-loop) -> hist -> scan -> scatter -> selfloop
// ---------------------------------------------------------------------------
__global__ void k_init_deg(int* __restrict__ deg)
{
    int i = blockIdx.x * blockDim.x + threadIdx.x;
    if (i < N_NODES) deg[i] = 1;      // self-loop
}

__global__ void k_hist(const int* __restrict__ dst, int* __restrict__ deg)
{
    for (int i = blockIdx.x * blockDim.x + threadIdx.x; i < NEDGE;
         i += gridDim.x * blockDim.x)
        atomicAdd(&deg[dst[i]], 1);
}

__global__ __launch_bounds__(1024) void k_reduce(const int* __restrict__ deg, int* __restrict__ bsum)
{
    __shared__ int s[1024];
    int i = blockIdx.x * 1024 + threadIdx.x;
    s[threadIdx.x] = (i < N_NODES) ? deg[i] : 0;
    __syncthreads();
    for (int d = 512; d > 0; d >>= 1) {
        if (threadIdx.x < d) s[threadIdx.x] += s[threadIdx.x + d];
        __syncthreads();
    }
    if (threadIdx.x == 0) bsum[blockIdx.x] = s[0];
}

__global__ void k_scan_bsum(const int* __restrict__ bsum, int* __restrict__ boff, int nb)
{
    if (blockIdx.x == 0 && threadIdx.x == 0) {
        int run = 0;
        for (int bb = 0; bb < nb; ++bb) { boff[bb] = run; run += bsum[bb]; }
    }
}

__global__ __launch_bounds__(1024) void k_scan(const int* __restrict__ deg, const int* __restrict__ boff,
                                               int* __restrict__ off, int* __restrict__ cursor)
{
    __shared__ int s[1024];
    int i = blockIdx.x * 1024 + threadIdx.x;
    int v = (i < N_NODES) ? deg[i] : 0;
    s[threadIdx.x] = v;
    __syncthreads();
    for (int d = 1; d < 1024; d <<= 1) {
        int tv = (threadIdx.x >= d) ? s[threadIdx.x - d] : 0;
        __syncthreads();
        s[threadIdx.x] += tv;
        __syncthreads();
    }
    int excl = s[threadIdx.x] - v + boff[blockIdx.x];
    if (i < N_NODES) { off[i] = excl; cursor[i] = excl; }
    if (i == N_NODES - 1) off[N_NODES] = excl + v;
}

__global__ void k_scatter(const int* __restrict__ src, const int* __restrict__ dst,
                          int* __restrict__ cursor, int* __restrict__ adj)
{
    for (int i = blockIdx.x * blockDim.x + threadIdx.x; i < NEDGE;
         i += gridDim.x * blockDim.x) {
        int p = atomicAdd(&cursor[dst[i]], 1);
        adj[p] = src[i];
    }
}

__global__ void k_selfloop(int* __restrict__ cursor, int* __restrict__ adj)
{
    int i = blockIdx.x * blockDim.x + threadIdx.x;
    if (i < N_NODES) { int p = atomicAdd(&cursor[i], 1); adj[p] = i; }
}

// ---------------------------------------------------------------------------
// GATv2 edge kernel: one node per 128 threads (tid = h*32+c), online softmax,
// single pass over incident edges, no atomics. Output = elu(acc/s + bo).
// ---------------------------------------------------------------------------
__global__ __launch_bounds__(256) void gat_edge(
    const float* __restrict__ xl, const float* __restrict__ xr,
    const float* __restrict__ att, const float* __restrict__ bo,
    const int* __restrict__ off, const int* __restrict__ adj,
    float* __restrict__ out)
{
    int node = blockIdx.x * 2 + (threadIdx.x >> 7);
    if (node >= N_NODES) return;
    int t = threadIdx.x & 127;            // h*32 + c
    float attv = att[t];
    float xrv = xr[node * F + t];
    int e0 = off[node], e1 = off[node + 1];

    float m = -1e30f, ssum = 0.f, acc = 0.f;
    int s0 = adj[e0];
    float xlv = xl[s0 * F + t];           // prefetched gather
    for (int e = e0; e < e1; ++e) {
        float xlc = xlv;
        if (e + 1 < e1) {                 // prefetch next edge
            int sn = adj[e + 1];
            xlv = xl[sn * F + t];
        }
        float z = xlc + xrv;
        z = fmaxf(z, 0.f) + 0.2f * fminf(z, 0.f);   // leaky_relu(z, 0.2)
        float term = z * attv;
        term += __shfl_xor(term, 16);     // reduce within 32-lane head group
        term += __shfl_xor(term, 8);
        term += __shfl_xor(term, 4);
        term += __shfl_xor(term, 2);
        term += __shfl_xor(term, 1);
        float nm = fmaxf(m, term);
        float corr = __expf(m - nm);
        float p = __expf(term - nm);
        ssum = ssum * corr + p;
        acc = acc * corr + p * xlc;
        m = nm;
    }
    float o = acc / ssum + bo[t];
    out[node * F + t] = (o > 0.f) ? o : expm1f(o);   // elu
}

// ---------------------------------------------------------------------------
// Final linear: out[n] = h[n,:] . W_f + b_f   (one wave per node)
// ---------------------------------------------------------------------------
__global__ void k_final(const float* __restrict__ h, const float* __restrict__ wf,
                        const float* __restrict__ bf, float* __restrict__ out)
{
    int gw = (blockIdx.x * blockDim.x + threadIdx.x) >> 6;
    int lane = threadIdx.x & 63;
    if (gw >= N_NODES) return;
    float v = h[gw * F + lane] * wf[lane] + h[gw * F + 64 + lane] * wf[64 + lane];
    v += __shfl_xor(v, 32); v += __shfl_xor(v, 16); v += __shfl_xor(v, 8);
    v += __shfl_xor(v, 4);  v += __shfl_xor(v, 2);  v += __shfl_xor(v, 1);
    if (lane == 0) out[gw] = v + bf[0];
}

// ---------------------------------------------------------------------------
extern "C" void kernel_launch(void* const* d_in, const int* in_sizes, int n_in,
                              void* d_out, int out_size, void* d_ws, size_t ws_size,
                              hipStream_t stream)
{
    const float* x    = (const float*)d_in[0];
    const int*   ei   = (const int*)  d_in[1];
    const float* W_l0 = (const float*)d_in[2];
    const float* b_l0 = (const float*)d_in[3];
    const float* W_r0 = (const float*)d_in[4];
    const float* b_r0 = (const float*)d_in[5];
    const float* att0 = (const float*)d_in[6];
    const float* bo0  = (const float*)d_in[7];
    const float* W_l  = (const float*)d_in[8];
    const float* b_l  = (const float*)d_in[9];
    const float* W_r  = (const float*)d_in[10];
    const float* b_r  = (const float*)d_in[11];
    const float* att  = (const float*)d_in[12];
    const float* bo   = (const float*)d_in[13];
    const float* W_f  = (const float*)d_in[14];
    const float* b_f  = (const float*)d_in[15];
    float* out = (float*)d_out;

    // workspace layout (256B-aligned regions), total ~81 MB
    char* ws = (char*)d_ws;
    size_t o = 0;
    auto alloc = [&](size_t bytes) { void* p = ws + o; o += (bytes + 255) & ~(size_t)255; return p; };
    float* xl  = (float*)alloc((size_t)N_NODES * F * 4);
    float* xr  = (float*)alloc((size_t)N_NODES * F * 4);
    float* hb  = (float*)alloc((size_t)N_NODES * F * 4);
    int* deg   = (int*)alloc((size_t)N_NODES * 4);
    int* off   = (int*)alloc((size_t)(N_NODES + 1) * 4);
    int* cur   = (int*)alloc((size_t)N_NODES * 4);
    int* adj   = (int*)alloc((size_t)(NEDGE + N_NODES) * 4);
    int* bsum  = (int*)alloc(64 * 4);
    int* boff  = (int*)alloc(64 * 4);

    const int* srcv = ei;
    const int* dstv = ei + NEDGE;

    // --- CSR build (every launch: ws is re-poisoned) ---
    k_init_deg<<<(N_NODES + 255) / 256, 256, 0, stream>>>(deg);
    k_hist<<<1024, 256, 0, stream>>>(dstv, deg);
    k_reduce<<<NB_SCAN, 1024, 0, stream>>>(deg, bsum);
    k_scan_bsum<<<1, 64, 0, stream>>>(bsum, boff, NB_SCAN);
    k_scan<<<NB_SCAN, 1024, 0, stream>>>(deg, boff, off, cur);
    k_scatter<<<1024, 256, 0, stream>>>(srcv, dstv, cur, adj);
    k_selfloop<<<(N_NODES + 255) / 256, 256, 0, stream>>>(cur, adj);

    // --- 3 GATv2 layers ---
    const float* Ain = x;
    for (int l = 0; l < 3; ++l) {
        const float *Wlp, *blp, *Wrp, *brp, *attp, *bop;
        if (l == 0) {
            Wlp = W_l0; blp = b_l0; Wrp = W_r0; brp = b_r0; attp = att0; bop = bo0;
        } else {
            Wlp = W_l + (size_t)(l - 1) * F * F;
            blp = b_l + (size_t)(l - 1) * F;
            Wrp = W_r + (size_t)(l - 1) * F * F;
            brp = b_r + (size_t)(l - 1) * F;
            attp = att + (size_t)(l - 1) * F;   // H*HID == 128
            bop = bo + (size_t)(l - 1) * F;
        }
        gemm128<<<dim3((N_NODES + 63) / 64, 2), 256, 0, stream>>>(
            Ain, Wlp, blp, Wrp, brp, xl, xr);
        gat_edge<<<(N_NODES + 1) / 2, 256, 0, stream>>>(xl, xr, attp, bop, off, adj, hb);
        Ain = hb;
    }

    // --- final linear [N,128] -> [N,1] ---
    k_final<<<(N_NODES + 3) / 4, 256, 0, stream>>>(hb, W_f, b_f, out);
}

// Round 4
// 565.895 us; speedup vs baseline: 1.6433x; 1.6433x over previous
//
#include <hip/hip_runtime.h>
#include <math.h>

#define N_NODES 50000
#define F 128          // feature width (IN == F_HID == 128)
#define NEDGE 800000
#define NB_SCAN 49     // ceil(N_NODES/1024)

// ---------------------------------------------------------------------------
// GEMM: O[n][c] = sum_k A[n][k]*W[k][c] + b[c];  A:[N,128], W:[128,128]
// blockIdx.y selects (Wl,bl,xl) vs (Wr,br,xr). BM=64, BN=128, BK=32.
// ---------------------------------------------------------------------------
__global__ __launch_bounds__(256) void gemm128(
    const float* __restrict__ A,
    const float* __restrict__ Wl, const float* __restrict__ bl,
    const float* __restrict__ Wr, const float* __restrict__ br,
    float* __restrict__ xl, float* __restrict__ xr)
{
    const float* W = blockIdx.y ? Wr : Wl;
    const float* b = blockIdx.y ? br : bl;
    float*       O = blockIdx.y ? xr : xl;

    __shared__ float As[32][68];   // transposed A tile, padded (272B rows, 16B-aligned)
    __shared__ float Ws[32][128];

    const int tid = threadIdx.x;
    const int tx = tid & 15, ty = tid >> 4;
    const int R0 = blockIdx.x * 64;

    float acc[4][8];
#pragma unroll
    for (int i = 0; i < 4; ++i)
#pragma unroll
        for (int j = 0; j < 8; ++j) acc[i][j] = 0.f;

    for (int kt = 0; kt < 4; ++kt) {
        // A tile 64x32 -> As (transposed)
#pragma unroll
        for (int i = 0; i < 2; ++i) {
            int f = tid + i * 256;          // 0..511
            int row = f >> 3, kq = f & 7;
            int gr = R0 + row;
            float4 v = make_float4(0.f, 0.f, 0.f, 0.f);
            if (gr < N_NODES) v = *(const float4*)&A[gr * F + kt * 32 + kq * 4];
            As[kq * 4 + 0][row] = v.x; As[kq * 4 + 1][row] = v.y;
            As[kq * 4 + 2][row] = v.z; As[kq * 4 + 3][row] = v.w;
        }
        // W tile 32x128
#pragma unroll
        for (int i = 0; i < 4; ++i) {
            int f = tid + i * 256;          // 0..1023
            int k = f >> 5, cq = f & 31;
            *(float4*)&Ws[k][cq * 4] = *(const float4*)&W[(kt * 32 + k) * F + cq * 4];
        }
        __syncthreads();
#pragma unroll
        for (int k = 0; k < 32; ++k) {
            float4 a4 = *(const float4*)&As[k][ty * 4];
            float4 w0 = *(const float4*)&Ws[k][tx * 8];
            float4 w1 = *(const float4*)&Ws[k][tx * 8 + 4];
            float av[4] = {a4.x, a4.y, a4.z, a4.w};
            float wv[8] = {w0.x, w0.y, w0.z, w0.w, w1.x, w1.y, w1.z, w1.w};
#pragma unroll
            for (int i = 0; i < 4; ++i)
#pragma unroll
                for (int j = 0; j < 8; ++j) acc[i][j] += av[i] * wv[j];
        }
        __syncthreads();
    }
#pragma unroll
    for (int i = 0; i < 4; ++i) {
        int gr = R0 + ty * 4 + i;
        if (gr < N_NODES) {
#pragma unroll
            for (int j = 0; j < 8; ++j) acc[i][j] += b[tx * 8 + j];
            *(float4*)&O[gr * F + tx * 8]     = make_float4(acc[i][0], acc[i][1], acc[i][2], acc[i][3]);
            *(float4*)&O[gr * F + tx * 8 + 4] = make_float4(acc[i][4], acc[i][5], acc[i][6], acc[i][7]);
        }
    }
}

// ---------------------------------------------------------------------------
// CSR build: deg (init 1 for self-loop) -> hist -> scan -> scatter -> selfloop
// ---------------------------------------------------------------------------
__global__ void k_init_deg(int* __restrict__ deg)
{
    int i = blockIdx.x * blockDim.x + threadIdx.x;
    if (i < N_NODES) deg[i] = 1;      // self-loop
}

__global__ void k_hist(const int* __restrict__ dst, int* __restrict__ deg)
{
    for (int i = blockIdx.x * blockDim.x + threadIdx.x; i < NEDGE;
         i += gridDim.x * blockDim.x)
        atomicAdd(&deg[dst[i]], 1);
}

__global__ __launch_bounds__(1024) void k_reduce(const int* __restrict__ deg, int* __restrict__ bsum)
{
    __shared__ int s[1024];
    int i = blockIdx.x * 1024 + threadIdx.x;
    s[threadIdx.x] = (i < N_NODES) ? deg[i] : 0;
    __syncthreads();
    for (int d = 512; d > 0; d >>= 1) {
        if (threadIdx.x < d) s[threadIdx.x] += s[threadIdx.x + d];
        __syncthreads();
    }
    if (threadIdx.x == 0) bsum[blockIdx.x] = s[0];
}

__global__ void k_scan_bsum(const int* __restrict__ bsum, int* __restrict__ boff, int nb)
{
    if (blockIdx.x == 0 && threadIdx.x == 0) {
        int run = 0;
        for (int bb = 0; bb < nb; ++bb) { boff[bb] = run; run += bsum[bb]; }
    }
}

__global__ __launch_bounds__(1024) void k_scan(const int* __restrict__ deg, const int* __restrict__ boff,
                                               int* __restrict__ off, int* __restrict__ cursor)
{
    __shared__ int s[1024];
    int i = blockIdx.x * 1024 + threadIdx.x;
    int v = (i < N_NODES) ? deg[i] : 0;
    s[threadIdx.x] = v;
    __syncthreads();
    for (int d = 1; d < 1024; d <<= 1) {
        int tv = (threadIdx.x >= d) ? s[threadIdx.x - d] : 0;
        __syncthreads();
        s[threadIdx.x] += tv;
        __syncthreads();
    }
    int excl = s[threadIdx.x] - v + boff[blockIdx.x];
    if (i < N_NODES) { off[i] = excl; cursor[i] = excl; }
    if (i == N_NODES - 1) off[N_NODES] = excl + v;
}

__global__ void k_scatter(const int* __restrict__ src, const int* __restrict__ dst,
                          int* __restrict__ cursor, int* __restrict__ adj)
{
    for (int i = blockIdx.x * blockDim.x + threadIdx.x; i < NEDGE;
         i += gridDim.x * blockDim.x) {
        int p = atomicAdd(&cursor[dst[i]], 1);
        adj[p] = src[i];
    }
}

__global__ void k_selfloop(int* __restrict__ cursor, int* __restrict__ adj)
{
    int i = blockIdx.x * blockDim.x + threadIdx.x;
    if (i < N_NODES) { int p = atomicAdd(&cursor[i], 1); adj[p] = i; }
}

// ---------------------------------------------------------------------------
// GATv2 edge kernel v2: 32 threads/node (thread t = channels 4t..4t+3,
// head = t>>3), float4 gathers, 4-deep rolling prefetch (named regs, static
// indexing), single-exp online softmax, 3-step shuffle reduce per 8-lane
// head group. Output = elu(acc/ssum + bo). No atomics, no LDS.
// ---------------------------------------------------------------------------
__global__ __launch_bounds__(256) void gat_edge(
    const float* __restrict__ xl, const float* __restrict__ xr,
    const float* __restrict__ att, const float* __restrict__ bo,
    const int* __restrict__ off, const int* __restrict__ adj,
    float* __restrict__ out)
{
    const int node = blockIdx.x * 8 + (threadIdx.x >> 5);
    if (node >= N_NODES) return;
    const int t = threadIdx.x & 31;            // channels 4t..4t+3
    const float4* __restrict__ xl4 = (const float4*)xl;
    const float4 attv = ((const float4*)att)[t];
    const float4 xrv  = ((const float4*)xr)[(size_t)node * 32 + t];
    const int e0 = off[node], e1 = off[node + 1];

    float m = -1e30f, ssum = 0.f;
    float4 acc = make_float4(0.f, 0.f, 0.f, 0.f);

    // 4-deep prefetch pipeline in named registers (no runtime indexing)
    float4 buf0, buf1, buf2, buf3;
    buf0 = buf1 = buf2 = buf3 = make_float4(0.f, 0.f, 0.f, 0.f);
    int eload = e0;
    if (eload < e1) { buf0 = xl4[(size_t)adj[eload] * 32 + t]; ++eload; }
    if (eload < e1) { buf1 = xl4[(size_t)adj[eload] * 32 + t]; ++eload; }
    if (eload < e1) { buf2 = xl4[(size_t)adj[eload] * 32 + t]; ++eload; }
    if (eload < e1) { buf3 = xl4[(size_t)adj[eload] * 32 + t]; ++eload; }

    for (int e = e0; e < e1; e += 4) {
#pragma unroll
        for (int j = 0; j < 4; ++j) {
            if (e + j < e1) {
                float4 xlc = (j == 0) ? buf0 : (j == 1) ? buf1 : (j == 2) ? buf2 : buf3;
                if (eload < e1) {               // refill slot j with edge e+j+4
                    float4 nv = xl4[(size_t)adj[eload] * 32 + t]; ++eload;
                    if (j == 0) buf0 = nv; else if (j == 1) buf1 = nv;
                    else if (j == 2) buf2 = nv; else buf3 = nv;
                }
                float z0 = xlc.x + xrv.x, z1 = xlc.y + xrv.y;
                float z2 = xlc.z + xrv.z, z3 = xlc.w + xrv.w;
                z0 = fmaxf(z0, 0.f) + 0.2f * fminf(z0, 0.f);   // leaky_relu 0.2
                z1 = fmaxf(z1, 0.f) + 0.2f * fminf(z1, 0.f);
                z2 = fmaxf(z2, 0.f) + 0.2f * fminf(z2, 0.f);
                z3 = fmaxf(z3, 0.f) + 0.2f * fminf(z3, 0.f);
                float term = z0 * attv.x + z1 * attv.y + z2 * attv.z + z3 * attv.w;
                term += __shfl_xor(term, 4);    // reduce within 8-lane head group
                term += __shfl_xor(term, 2);
                term += __shfl_xor(term, 1);
                // single-exp online softmax update
                float d  = term - m;
                float ev = __expf(-fabsf(d));
                float corr = (d > 0.f) ? ev : 1.f;
                float p    = (d > 0.f) ? 1.f : ev;
                m = fmaxf(m, term);
                ssum  = ssum  * corr + p;
                acc.x = acc.x * corr + p * xlc.x;
                acc.y = acc.y * corr + p * xlc.y;
                acc.z = acc.z * corr + p * xlc.z;
                acc.w = acc.w * corr + p * xlc.w;
            }
        }
    }
    const float inv = 1.f / ssum;
    const float4 bov = ((const float4*)bo)[t];
    float4 o;
    o.x = acc.x * inv + bov.x;
    o.y = acc.y * inv + bov.y;
    o.z = acc.z * inv + bov.z;
    o.w = acc.w * inv + bov.w;
    o.x = (o.x > 0.f) ? o.x : expm1f(o.x);     // elu
    o.y = (o.y > 0.f) ? o.y : expm1f(o.y);
    o.z = (o.z > 0.f) ? o.z : expm1f(o.z);
    o.w = (o.w > 0.f) ? o.w : expm1f(o.w);
    ((float4*)out)[(size_t)node * 32 + t] = o;
}

// ---------------------------------------------------------------------------
// Final linear: out[n] = h[n,:] . W_f + b_f   (one wave per node)
// ---------------------------------------------------------------------------
__global__ void k_final(const float* __restrict__ h, const float* __restrict__ wf,
                        const float* __restrict__ bf, float* __restrict__ out)
{
    int gw = (blockIdx.x * blockDim.x + threadIdx.x) >> 6;
    int lane = threadIdx.x & 63;
    if (gw >= N_NODES) return;
    float v = h[gw * F + lane] * wf[lane] + h[gw * F + 64 + lane] * wf[64 + lane];
    v += __shfl_xor(v, 32); v += __shfl_xor(v, 16); v += __shfl_xor(v, 8);
    v += __shfl_xor(v, 4);  v += __shfl_xor(v, 2);  v += __shfl_xor(v, 1);
    if (lane == 0) out[gw] = v + bf[0];
}

// ---------------------------------------------------------------------------
extern "C" void kernel_launch(void* const* d_in, const int* in_sizes, int n_in,
                              void* d_out, int out_size, void* d_ws, size_t ws_size,
                              hipStream_t stream)
{
    const float* x    = (const float*)d_in[0];
    const int*   ei   = (const int*)  d_in[1];
    const float* W_l0 = (const float*)d_in[2];
    const float* b_l0 = (const float*)d_in[3];
    const float* W_r0 = (const float*)d_in[4];
    const float* b_r0 = (const float*)d_in[5];
    const float* att0 = (const float*)d_in[6];
    const float* bo0  = (const float*)d_in[7];
    const float* W_l  = (const float*)d_in[8];
    const float* b_l  = (const float*)d_in[9];
    const float* W_r  = (const float*)d_in[10];
    const float* b_r  = (const float*)d_in[11];
    const float* att  = (const float*)d_in[12];
    const float* bo   = (const float*)d_in[13];
    const float* W_f  = (const float*)d_in[14];
    const float* b_f  = (const float*)d_in[15];
    float* out = (float*)d_out;

    // workspace layout (256B-aligned regions), total ~81 MB
    char* ws = (char*)d_ws;
    size_t o = 0;
    auto alloc = [&](size_t bytes) { void* p = ws + o; o += (bytes + 255) & ~(size_t)255; return p; };
    float* xl  = (float*)alloc((size_t)N_NODES * F * 4);
    float* xr  = (float*)alloc((size_t)N_NODES * F * 4);
    float* hb  = (float*)alloc((size_t)N_NODES * F * 4);
    int* deg   = (int*)alloc((size_t)N_NODES * 4);
    int* off   = (int*)alloc((size_t)(N_NODES + 1) * 4);
    int* cur   = (int*)alloc((size_t)N_NODES * 4);
    int* adj   = (int*)alloc((size_t)(NEDGE + N_NODES) * 4);
    int* bsum  = (int*)alloc(64 * 4);
    int* boff  = (int*)alloc(64 * 4);

    const int* srcv = ei;
    const int* dstv = ei + NEDGE;

    // --- CSR build (every launch: ws is re-poisoned) ---
    k_init_deg<<<(N_NODES + 255) / 256, 256, 0, stream>>>(deg);
    k_hist<<<1024, 256, 0, stream>>>(dstv, deg);
    k_reduce<<<NB_SCAN, 1024, 0, stream>>>(deg, bsum);
    k_scan_bsum<<<1, 64, 0, stream>>>(bsum, boff, NB_SCAN);
    k_scan<<<NB_SCAN, 1024, 0, stream>>>(deg, boff, off, cur);
    k_scatter<<<1024, 256, 0, stream>>>(srcv, dstv, cur, adj);
    k_selfloop<<<(N_NODES + 255) / 256, 256, 0, stream>>>(cur, adj);

    // --- 3 GATv2 layers ---
    const float* Ain = x;
    for (int l = 0; l < 3; ++l) {
        const float *Wlp, *blp, *Wrp, *brp, *attp, *bop;
        if (l == 0) {
            Wlp = W_l0; blp = b_l0; Wrp = W_r0; brp = b_r0; attp = att0; bop = bo0;
        } else {
            Wlp = W_l + (size_t)(l - 1) * F * F;
            blp = b_l + (size_t)(l - 1) * F;
            Wrp = W_r + (size_t)(l - 1) * F * F;
            brp = b_r + (size_t)(l - 1) * F;
            attp = att + (size_t)(l - 1) * F;   // H*HID == 128
            bop = bo + (size_t)(l - 1) * F;
        }
        gemm128<<<dim3((N_NODES + 63) / 64, 2), 256, 0, stream>>>(
            Ain, Wlp, blp, Wrp, brp, xl, xr);
        gat_edge<<<(N_NODES + 7) / 8, 256, 0, stream>>>(xl, xr, attp, bop, off, adj, hb);
        Ain = hb;
    }

    // --- final linear [N,128] -> [N,1] ---
    k_final<<<(N_NODES + 3) / 4, 256, 0, stream>>>(hb, W_f, b_f, out);
}

// Round 6
// 547.761 us; speedup vs baseline: 1.6977x; 1.0331x over previous
//
#include <hip/hip_runtime.h>
#include <math.h>

#define N_NODES 50000
#define F 128          // feature width (IN == F_HID == 128)
#define NEDGE 800000
#define NB_SCAN 49     // ceil(N_NODES/1024)

static __device__ __forceinline__ int imin(int a, int b) { return a < b ? a : b; }

// ---------------------------------------------------------------------------
// GEMM: O[n][c] = sum_k A[n][k]*W[k][c] + b[c];  A:[N,128], W:[128,128]
// blockIdx.y selects (Wl,bl,xl) vs (Wr,br,xr). BM=64, BN=128, BK=32.
// ---------------------------------------------------------------------------
__global__ __launch_bounds__(256) void gemm128(
    const float* __restrict__ A,
    const float* __restrict__ Wl, const float* __restrict__ bl,
    const float* __restrict__ Wr, const float* __restrict__ br,
    float* __restrict__ xl, float* __restrict__ xr)
{
    const float* W = blockIdx.y ? Wr : Wl;
    const float* b = blockIdx.y ? br : bl;
    float*       O = blockIdx.y ? xr : xl;

    __shared__ float As[32][68];   // transposed A tile, padded (272B rows, 16B-aligned)
    __shared__ float Ws[32][128];

    const int tid = threadIdx.x;
    const int tx = tid & 15, ty = tid >> 4;
    const int R0 = blockIdx.x * 64;

    float acc[4][8];
#pragma unroll
    for (int i = 0; i < 4; ++i)
#pragma unroll
        for (int j = 0; j < 8; ++j) acc[i][j] = 0.f;

    for (int kt = 0; kt < 4; ++kt) {
        // A tile 64x32 -> As (transposed)
#pragma unroll
        for (int i = 0; i < 2; ++i) {
            int f = tid + i * 256;          // 0..511
            int row = f >> 3, kq = f & 7;
            int gr = R0 + row;
            float4 v = make_float4(0.f, 0.f, 0.f, 0.f);
            if (gr < N_NODES) v = *(const float4*)&A[gr * F + kt * 32 + kq * 4];
            As[kq * 4 + 0][row] = v.x; As[kq * 4 + 1][row] = v.y;
            As[kq * 4 + 2][row] = v.z; As[kq * 4 + 3][row] = v.w;
        }
        // W tile 32x128
#pragma unroll
        for (int i = 0; i < 4; ++i) {
            int f = tid + i * 256;          // 0..1023
            int k = f >> 5, cq = f & 31;
            *(float4*)&Ws[k][cq * 4] = *(const float4*)&W[(kt * 32 + k) * F + cq * 4];
        }
        __syncthreads();
#pragma unroll
        for (int k = 0; k < 32; ++k) {
            float4 a4 = *(const float4*)&As[k][ty * 4];
            float4 w0 = *(const float4*)&Ws[k][tx * 8];
            float4 w1 = *(const float4*)&Ws[k][tx * 8 + 4];
            float av[4] = {a4.x, a4.y, a4.z, a4.w};
            float wv[8] = {w0.x, w0.y, w0.z, w0.w, w1.x, w1.y, w1.z, w1.w};
#pragma unroll
            for (int i = 0; i < 4; ++i)
#pragma unroll
                for (int j = 0; j < 8; ++j) acc[i][j] += av[i] * wv[j];
        }
        __syncthreads();
    }
#pragma unroll
    for (int i = 0; i < 4; ++i) {
        int gr = R0 + ty * 4 + i;
        if (gr < N_NODES) {
#pragma unroll
            for (int j = 0; j < 8; ++j) acc[i][j] += b[tx * 8 + j];
            *(float4*)&O[gr * F + tx * 8]     = make_float4(acc[i][0], acc[i][1], acc[i][2], acc[i][3]);
            *(float4*)&O[gr * F + tx * 8 + 4] = make_float4(acc[i][4], acc[i][5], acc[i][6], acc[i][7]);
        }
    }
}

// ---------------------------------------------------------------------------
// CSR build: deg (init 1 for self-loop) -> hist -> scan -> scatter -> selfloop
// ---------------------------------------------------------------------------
__global__ void k_init_deg(int* __restrict__ deg)
{
    int i = blockIdx.x * blockDim.x + threadIdx.x;
    if (i < N_NODES) deg[i] = 1;      // self-loop
}

__global__ void k_hist(const int* __restrict__ dst, int* __restrict__ deg)
{
    for (int i = blockIdx.x * blockDim.x + threadIdx.x; i < NEDGE;
         i += gridDim.x * blockDim.x)
        atomicAdd(&deg[dst[i]], 1);
}

__global__ __launch_bounds__(1024) void k_reduce(const int* __restrict__ deg, int* __restrict__ bsum)
{
    __shared__ int s[1024];
    int i = blockIdx.x * 1024 + threadIdx.x;
    s[threadIdx.x] = (i < N_NODES) ? deg[i] : 0;
    __syncthreads();
    for (int d = 512; d > 0; d >>= 1) {
        if (threadIdx.x < d) s[threadIdx.x] += s[threadIdx.x + d];
        __syncthreads();
    }
    if (threadIdx.x == 0) bsum[blockIdx.x] = s[0];
}

__global__ void k_scan_bsum(const int* __restrict__ bsum, int* __restrict__ boff, int nb)
{
    if (blockIdx.x == 0 && threadIdx.x == 0) {
        int run = 0;
        for (int bb = 0; bb < nb; ++bb) { boff[bb] = run; run += bsum[bb]; }
    }
}

__global__ __launch_bounds__(1024) void k_scan(const int* __restrict__ deg, const int* __restrict__ boff,
                                               int* __restrict__ off, int* __restrict__ cursor)
{
    __shared__ int s[1024];
    int i = blockIdx.x * 1024 + threadIdx.x;
    int v = (i < N_NODES) ? deg[i] : 0;
    s[threadIdx.x] = v;
    __syncthreads();
    for (int d = 1; d < 1024; d <<= 1) {
        int tv = (threadIdx.x >= d) ? s[threadIdx.x - d] : 0;
        __syncthreads();
        s[threadIdx.x] += tv;
        __syncthreads();
    }
    int excl = s[threadIdx.x] - v + boff[blockIdx.x];
    int i2 = i;
    if (i2 < N_NODES) { off[i2] = excl; cursor[i2] = excl; }
    if (i2 == N_NODES - 1) off[N_NODES] = excl + v;
}

__global__ void k_scatter(const int* __restrict__ src, const int* __restrict__ dst,
                          int* __restrict__ cursor, int* __restrict__ adj)
{
    for (int i = blockIdx.x * blockDim.x + threadIdx.x; i < NEDGE;
         i += gridDim.x * blockDim.x) {
        int p = atomicAdd(&cursor[dst[i]], 1);
        adj[p] = src[i];
    }
}

__global__ void k_selfloop(int* __restrict__ cursor, int* __restrict__ adj)
{
    int i = blockIdx.x * blockDim.x + threadIdx.x;
    if (i < N_NODES) { int p = atomicAdd(&cursor[i], 1); adj[p] = i; }
}

// ---------------------------------------------------------------------------
// GATv2 edge kernel v3: 32 threads/node, float4 gathers, branch-free quad
// main loop (clamped prefetch indices), quad-merged online softmax: 4
// independent terms -> 1 max-tree -> 1 correction exp + 4 independent exps
// -> fused state update. Tail (deg&3) uses single-edge updates on the
// already-prefetched buffers. No atomics, no LDS.
// ---------------------------------------------------------------------------
__device__ __forceinline__ float edge_term(const float4 xlc, const float4 xrv,
                                           const float4 attv)
{
    float z0 = xlc.x + xrv.x, z1 = xlc.y + xrv.y;
    float z2 = xlc.z + xrv.z, z3 = xlc.w + xrv.w;
    z0 = fmaxf(z0, 0.f) + 0.2f * fminf(z0, 0.f);   // leaky_relu 0.2
    z1 = fmaxf(z1, 0.f) + 0.2f * fminf(z1, 0.f);
    z2 = fmaxf(z2, 0.f) + 0.2f * fminf(z2, 0.f);
    z3 = fmaxf(z3, 0.f) + 0.2f * fminf(z3, 0.f);
    float term = z0 * attv.x + z1 * attv.y + z2 * attv.z + z3 * attv.w;
    term += __shfl_xor(term, 4);    // reduce within 8-lane head group
    term += __shfl_xor(term, 2);
    term += __shfl_xor(term, 1);
    return term;
}

__global__ __launch_bounds__(256) void gat_edge(
    const float* __restrict__ xl, const float* __restrict__ xr,
    const float* __restrict__ att, const float* __restrict__ bo,
    const int* __restrict__ off, const int* __restrict__ adj,
    float* __restrict__ out)
{
    const int node = blockIdx.x * 8 + (threadIdx.x >> 5);
    if (node >= N_NODES) return;
    const int t = threadIdx.x & 31;            // channels 4t..4t+3
    const float4* __restrict__ xl4 = (const float4*)xl;
    const float4 attv = ((const float4*)att)[t];
    const float4 xrv  = ((const float4*)xr)[(size_t)node * 32 + t];
    const int e0 = off[node], e1 = off[node + 1];
    const int deg = e1 - e0;                   // >= 1 (self-loop)
    const int nq = deg >> 2, rem = deg & 3;
    const int elast = e1 - 1;

    float m = -1e30f, ssum = 0.f;
    float4 acc = make_float4(0.f, 0.f, 0.f, 0.f);

    // prefetch quad 0 (clamped indices: always in-bounds, no branches)
    int base = e0;
    float4 buf0 = xl4[(size_t)adj[imin(base + 0, elast)] * 32 + t];
    float4 buf1 = xl4[(size_t)adj[imin(base + 1, elast)] * 32 + t];
    float4 buf2 = xl4[(size_t)adj[imin(base + 2, elast)] * 32 + t];
    float4 buf3 = xl4[(size_t)adj[imin(base + 3, elast)] * 32 + t];

    for (int q = 0; q < nq; ++q) {
        float4 x0 = buf0, x1 = buf1, x2 = buf2, x3 = buf3;
        base += 4;
        // prefetch next quad (clamped; tail duplicates are harmless)
        buf0 = xl4[(size_t)adj[imin(base + 0, elast)] * 32 + t];
        buf1 = xl4[(size_t)adj[imin(base + 1, elast)] * 32 + t];
        buf2 = xl4[(size_t)adj[imin(base + 2, elast)] * 32 + t];
        buf3 = xl4[(size_t)adj[imin(base + 3, elast)] * 32 + t];

        // 4 independent edge terms
        float t0 = edge_term(x0, xrv, attv);
        float t1 = edge_term(x1, xrv, attv);
        float t2 = edge_term(x2, xrv, attv);
        float t3 = edge_term(x3, xrv, attv);

        // quad-merged online softmax update (1 dependent exp per quad)
        float qm = fmaxf(fmaxf(t0, t1), fmaxf(t2, t3));
        float nm = fmaxf(m, qm);
        float corr = __expf(m - nm);
        float p0 = __expf(t0 - nm);
        float p1 = __expf(t1 - nm);
        float p2 = __expf(t2 - nm);
        float p3 = __expf(t3 - nm);
        m = nm;
        ssum  = ssum  * corr + ((p0 + p1) + (p2 + p3));
        acc.x = acc.x * corr + (p0 * x0.x + p1 * x1.x + p2 * x2.x + p3 * x3.x);
        acc.y = acc.y * corr + (p0 * x0.y + p1 * x1.y + p2 * x2.y + p3 * x3.y);
        acc.z = acc.z * corr + (p0 * x0.z + p1 * x1.z + p2 * x2.z + p3 * x3.z);
        acc.w = acc.w * corr + (p0 * x0.w + p1 * x1.w + p2 * x2.w + p3 * x3.w);
    }

    // tail: rem in [0,3]; genuine edges are already in buf0..buf2
    if (rem > 0) {
        float tt = edge_term(buf0, xrv, attv);
        float d = tt - m, ev = __expf(-fabsf(d));
        float corr = (d > 0.f) ? ev : 1.f, p = (d > 0.f) ? 1.f : ev;
        m = fmaxf(m, tt);
        ssum  = ssum  * corr + p;
        acc.x = acc.x * corr + p * buf0.x;  acc.y = acc.y * corr + p * buf0.y;
        acc.z = acc.z * corr + p * buf0.z;  acc.w = acc.w * corr + p * buf0.w;
    }
    if (rem > 1) {
        float tt = edge_term(buf1, xrv, attv);
        float d = tt - m, ev = __expf(-fabsf(d));
        float corr = (d > 0.f) ? ev : 1.f, p = (d > 0.f) ? 1.f : ev;
        m = fmaxf(m, tt);
        ssum  = ssum  * corr + p;
        acc.x = acc.x * corr + p * buf1.x;  acc.y = acc.y * corr + p * buf1.y;
        acc.z = acc.z * corr + p * buf1.z;  acc.w = acc.w * corr + p * buf1.w;
    }
    if (rem > 2) {
        float tt = edge_term(buf2, xrv, attv);
        float d = tt - m, ev = __expf(-fabsf(d));
        float corr = (d > 0.f) ? ev : 1.f, p = (d > 0.f) ? 1.f : ev;
        m = fmaxf(m, tt);
        ssum  = ssum  * corr + p;
        acc.x = acc.x * corr + p * buf2.x;  acc.y = acc.y * corr + p * buf2.y;
        acc.z = acc.z * corr + p * buf2.z;  acc.w = acc.w * corr + p * buf2.w;
    }

    const float inv = 1.f / ssum;
    const float4 bov = ((const float4*)bo)[t];
    float4 o;
    o.x = acc.x * inv + bov.x;
    o.y = acc.y * inv + bov.y;
    o.z = acc.z * inv + bov.z;
    o.w = acc.w * inv + bov.w;
    o.x = (o.x > 0.f) ? o.x : expm1f(o.x);     // elu
    o.y = (o.y > 0.f) ? o.y : expm1f(o.y);
    o.z = (o.z > 0.f) ? o.z : expm1f(o.z);
    o.w = (o.w > 0.f) ? o.w : expm1f(o.w);
    ((float4*)out)[(size_t)node * 32 + t] = o;
}

// ---------------------------------------------------------------------------
// Final linear: out[n] = h[n,:] . W_f + b_f   (one wave per node)
// ---------------------------------------------------------------------------
__global__ void k_final(const float* __restrict__ h, const float* __restrict__ wf,
                        const float* __restrict__ bf, float* __restrict__ out)
{
    int gw = (blockIdx.x * blockDim.x + threadIdx.x) >> 6;
    int lane = threadIdx.x & 63;
    if (gw >= N_NODES) return;
    float v = h[gw * F + lane] * wf[lane] + h[gw * F + 64 + lane] * wf[64 + lane];
    v += __shfl_xor(v, 32); v += __shfl_xor(v, 16); v += __shfl_xor(v, 8);
    v += __shfl_xor(v, 4);  v += __shfl_xor(v, 2);  v += __shfl_xor(v, 1);
    if (lane == 0) out[gw] = v + bf[0];
}

// ---------------------------------------------------------------------------
extern "C" void kernel_launch(void* const* d_in, const int* in_sizes, int n_in,
                              void* d_out, int out_size, void* d_ws, size_t ws_size,
                              hipStream_t stream)
{
    const float* x    = (const float*)d_in[0];
    const int*   ei   = (const int*)  d_in[1];
    const float* W_l0 = (const float*)d_in[2];
    const float* b_l0 = (const float*)d_in[3];
    const float* W_r0 = (const float*)d_in[4];
    const float* b_r0 = (const float*)d_in[5];
    const float* att0 = (const float*)d_in[6];
    const float* bo0  = (const float*)d_in[7];
    const float* W_l  = (const float*)d_in[8];
    const float* b_l  = (const float*)d_in[9];
    const float* W_r  = (const float*)d_in[10];
    const float* b_r  = (const float*)d_in[11];
    const float* att  = (const float*)d_in[12];
    const float* bo   = (const float*)d_in[13];
    const float* W_f  = (const float*)d_in[14];
    const float* b_f  = (const float*)d_in[15];
    float* out = (float*)d_out;

    // workspace layout (256B-aligned regions), total ~81 MB
    char* ws = (char*)d_ws;
    size_t o = 0;
    auto alloc = [&](size_t bytes) { void* p = ws + o; o += (bytes + 255) & ~(size_t)255; return p; };
    float* xl  = (float*)alloc((size_t)N_NODES * F * 4);
    float* xr  = (float*)alloc((size_t)N_NODES * F * 4);
    float* hb  = (float*)alloc((size_t)N_NODES * F * 4);
    int* deg   = (int*)alloc((size_t)N_NODES * 4);
    int* off   = (int*)alloc((size_t)(N_NODES + 1) * 4);
    int* cur   = (int*)alloc((size_t)N_NODES * 4);
    int* adj   = (int*)alloc((size_t)(NEDGE + N_NODES) * 4);
    int* bsum  = (int*)alloc(64 * 4);
    int* boff  = (int*)alloc(64 * 4);

    const int* srcv = ei;
    const int* dstv = ei + NEDGE;

    // --- CSR build (every launch: ws is re-poisoned) ---
    k_init_deg<<<(N_NODES + 255) / 256, 256, 0, stream>>>(deg);
    k_hist<<<1024, 256, 0, stream>>>(dstv, deg);
    k_reduce<<<NB_SCAN, 1024, 0, stream>>>(deg, bsum);
    k_scan_bsum<<<1, 64, 0, stream>>>(bsum, boff, NB_SCAN);
    k_scan<<<NB_SCAN, 1024, 0, stream>>>(deg, boff, off, cur);
    k_scatter<<<1024, 256, 0, stream>>>(srcv, dstv, cur, adj);
    k_selfloop<<<(N_NODES + 255) / 256, 256, 0, stream>>>(cur, adj);

    // --- 3 GATv2 layers ---
    const float* Ain = x;
    for (int l = 0; l < 3; ++l) {
        const float *Wlp, *blp, *Wrp, *brp, *attp, *bop;
        if (l == 0) {
            Wlp = W_l0; blp = b_l0; Wrp = W_r0; brp = b_r0; attp = att0; bop = bo0;
        } else {
            Wlp = W_l + (size_t)(l - 1) * F * F;
            blp = b_l + (size_t)(l - 1) * F;
            Wrp = W_r + (size_t)(l - 1) * F * F;
            brp = b_r + (size_t)(l - 1) * F;
            attp = att + (size_t)(l - 1) * F;   // H*HID == 128
            bop = bo + (size_t)(l - 1) * F;
        }
        gemm128<<<dim3((N_NODES + 63) / 64, 2), 256, 0, stream>>>(
            Ain, Wlp, blp, Wrp, brp, xl, xr);
        gat_edge<<<(N_NODES + 7) / 8, 256, 0, stream>>>(xl, xr, attp, bop, off, adj, hb);
        Ain = hb;
    }

    // --- final linear [N,128] -> [N,1] ---
    k_final<<<(N_NODES + 3) / 4, 256, 0, stream>>>(hb, W_f, b_f, out);
}